// Round 7
// baseline (430.076 us; speedup 1.0000x reference)
//
#include <hip/hip_runtime.h>

// LIF neuron scan: x [T=16, B=32, C=128, H=32, W=32] fp32 -> spikes same shape.
//   u1   = mem*0.5 + x*0.5 ; spk = (u1 > 1) ; mem' = spk ? 0 : u1
// Sequential only in T; all B*C*H*W positions independent.
//
// History:
//  R1: 1 col/thread — latency-bound: 2 KB per serialized round trip; 2.3 TB/s.
//  R3/R4: cross-iteration register hoist (+sched_barrier) — compiler sank it.
//  R5: inline-asm hoist — ALU uses escaped above the waitcnt => wrong data.
//  R6: 4 block-strided cols/thread, in-iteration load batch — WIN. Kernel
//      dropped below the 164 us harness memsets (was 167 us). Confirmed:
//      bytes-in-flight per round trip is the binding resource.
//  R7 (this): COLS 4 -> 8 (8 KB/wave per round trip), phase-separated
//      load/compute/store per t-step to keep the load batch contiguous.

constexpr int   T_STEPS     = 16;
constexpr int   COLS        = 8;      // float4 columns per thread
constexpr float DECAY       = 0.5f;   // 1 - 1/tau, tau=2
constexpr float INPUT_SCALE = 0.5f;   // 1/tau
constexpr float THRESH      = 1.0f;

typedef float floatx4 __attribute__((ext_vector_type(4)));

__global__ __launch_bounds__(256) void lif_scan_kernel(
    const float* __restrict__ x,
    float*       __restrict__ out,
    int n_per_t)                      // elements per time slice (4,194,304)
{
    const int n4 = n_per_t >> 2;                       // float4s per slice
    // Block-strided columns: lane-adjacent addresses within each load inst.
    const int f4_base = blockIdx.x * (256 * COLS) + threadIdx.x;

    const floatx4* __restrict__ xin  = reinterpret_cast<const floatx4*>(x);
    floatx4*       __restrict__ outv = reinterpret_cast<floatx4*>(out);

    floatx4 mem[COLS];
    #pragma unroll
    for (int c = 0; c < COLS; ++c) mem[c] = (floatx4)(0.f);

    #pragma unroll
    for (int t = 0; t < T_STEPS; ++t) {
        const size_t slice = (size_t)t * (size_t)n4 + (size_t)f4_base;

        // Phase A: 8 independent coalesced loads, batched back-to-back.
        floatx4 v[COLS];
        #pragma unroll
        for (int c = 0; c < COLS; ++c)
            v[c] = xin[slice + c * 256];

        // Phase B: compute all columns (waits retire loads progressively).
        floatx4 s[COLS];
        #pragma unroll
        for (int c = 0; c < COLS; ++c) {
            #pragma unroll
            for (int k = 0; k < 4; ++k) {
                const float u = mem[c][k] * DECAY + v[c][k] * INPUT_SCALE;
                s[c][k]       = (u > THRESH) ? 1.0f : 0.0f;
                mem[c][k]     = (u > THRESH) ? 0.0f : u;
            }
        }

        // Phase C: 8 streaming stores (nothing in-kernel waits on them).
        #pragma unroll
        for (int c = 0; c < COLS; ++c)
            outv[slice + c * 256] = s[c];
    }
}

extern "C" void kernel_launch(void* const* d_in, const int* in_sizes, int n_in,
                              void* d_out, int out_size, void* d_ws, size_t ws_size,
                              hipStream_t stream) {
    const float* x   = (const float*)d_in[0];
    float*       out = (float*)d_out;

    const int total   = in_sizes[0];          // T * B * C * H * W
    const int n_per_t = total / T_STEPS;      // 4,194,304

    const int threads = 256;
    const int n4      = n_per_t / 4;          // 1,048,576 float4s per slice
    const int blocks  = n4 / (threads * COLS);  // 512 blocks

    lif_scan_kernel<<<blocks, threads, 0, stream>>>(x, out, n_per_t);
}